// Round 5
// baseline (169.545 us; speedup 1.0000x reference)
//
#include <hip/hip_runtime.h>
#include <hip/hip_bf16.h>

typedef __attribute__((ext_vector_type(8))) short short8;
typedef __attribute__((ext_vector_type(4))) float floatx4;

#define BDIM 128
#define RDIM 1024
#define NB   4096
#define NG   16
#define LDW  68     // padded LDS row stride (shorts) for BK=64 tiles: 136 B
#define WST  136    // padded W row stride (shorts) in k_newbb: 272 B

// ws byte offsets
#define OFF_MEANH   0                          // 4096*128 bf16   = 1 MB
#define OFF_RFH     (1u << 20)                 // 4096*1024 bf16  = 8 MB
#define OFF_WRFRFH  (9u << 20)                 // 1024*1024 bf16  = 2 MB
#define OFF_WBBRFH  (11u << 20)                // 1024*128 bf16   = 256 KB
#define OFF_WRFBBH  (OFF_WBBRFH + (1u << 18))  // 128*1024 bf16   = 256 KB
#define OFF_WBBBBH  (OFF_WRFBBH + (1u << 18))  // 128*128 bf16    = 32 KB
#define OFF_RF2BB   (12u << 20)                // 4096*128 fp32   = 2 MB

__device__ __forceinline__ float mishf(float x) {
    float e = __expf(x);
    float t = e * (e + 2.0f);
    float r = x * (t / (t + 2.0f));
    return x > 20.0f ? x : r;
}

__device__ __forceinline__ short8 cvt8v(float4 f0, float4 f1) {
    union { __hip_bfloat162 h; unsigned u; } c0, c1, c2, c3;
    c0.h = __float22bfloat162_rn(make_float2(f0.x, f0.y));
    c1.h = __float22bfloat162_rn(make_float2(f0.z, f0.w));
    c2.h = __float22bfloat162_rn(make_float2(f1.x, f1.y));
    c3.h = __float22bfloat162_rn(make_float2(f1.z, f1.w));
    union { short8 s; unsigned u[4]; } r;
    r.u[0] = c0.u; r.u[1] = c1.u; r.u[2] = c2.u; r.u[3] = c3.u;
    return r.s;
}

#define MFMA(a, b, c) __builtin_amdgcn_mfma_f32_16x16x32_bf16(a, b, c, 0, 0, 0)

// ---------------- prep: mean(BB)->bf16 + fp32->bf16 conversions ----------------
__global__ void __launch_bounds__(256) k_prep(
    const float* __restrict__ bb, const float* __restrict__ rf,
    const float* __restrict__ Wrfrf, const float* __restrict__ Wbbrf,
    const float* __restrict__ Wrfbb, const float* __restrict__ Wbbbb,
    short* __restrict__ meanh, short* __restrict__ rfh,
    short* __restrict__ wrfrfh, short* __restrict__ wbbrfh,
    short* __restrict__ wrfbbh, short* __restrict__ wbbbbh)
{
    int blk = blockIdx.x, tid = threadIdx.x;
    if (blk < 256) {
        int gt = blk * 256 + tid;          // 65536 threads
        int b = gt >> 4, d = (gt & 15) * 8;
        const float* p = bb + (size_t)b * (NG * BDIM) + d;
        float4 s0 = {0.f,0.f,0.f,0.f}, s1 = s0;
        #pragma unroll
        for (int g = 0; g < NG; ++g) {
            float4 v0 = ((const float4*)(p + g * BDIM))[0];
            float4 v1 = ((const float4*)(p + g * BDIM))[1];
            s0.x += v0.x; s0.y += v0.y; s0.z += v0.z; s0.w += v0.w;
            s1.x += v1.x; s1.y += v1.y; s1.z += v1.z; s1.w += v1.w;
        }
        s0.x *= 0.0625f; s0.y *= 0.0625f; s0.z *= 0.0625f; s0.w *= 0.0625f;
        s1.x *= 0.0625f; s1.y *= 0.0625f; s1.z *= 0.0625f; s1.w *= 0.0625f;
        *(short8*)(meanh + (size_t)b * BDIM + d) = cvt8v(s0, s1);
    } else {
        const int total = 524288 + 131072 + 16384 + 16384 + 2048; // short8 chunks
        int c0 = (blk - 256) * 256 + tid;
        int stride = ((int)gridDim.x - 256) * 256;
        for (int c = c0; c < total; c += stride) {
            const float* src; short* dst; int i = c;
            if (i < 524288)                { src = rf;    dst = rfh; }
            else if ((i -= 524288) < 131072) { src = Wrfrf; dst = wrfrfh; }
            else if ((i -= 131072) < 16384)  { src = Wbbrf; dst = wbbrfh; }
            else if ((i -= 16384) < 16384)   { src = Wrfbb; dst = wrfbbh; }
            else     { i -= 16384;             src = Wbbbb; dst = wbbbbh; }
            const float4* s = (const float4*)(src + (size_t)i * 8);
            *(short8*)(dst + (size_t)i * 8) = cvt8v(s[0], s[1]);
        }
    }
}

// ---- new_RF = mish(RF@Wrfrf^T+b1) + mish(mean@Wbbrf^T+b2); also rf2bb slices ----
// 512 blocks x 256 thr; block tile 128(M)x64(N); BK=64; all-bf16; dbuf, 1 barrier/half.
__global__ void __launch_bounds__(256) k_newrf(
    const short* __restrict__ rfh,     // [4096,1024] bf16
    const short* __restrict__ meanh,   // [4096,128]  bf16
    const short* __restrict__ wrfrfh,  // [1024,1024] bf16
    const float* __restrict__ brfrf,   // [1024]
    const short* __restrict__ wbbrfh,  // [1024,128]  bf16
    const float* __restrict__ bbbrf,   // [1024]
    const short* __restrict__ wrfbbh,  // [128,1024]  bf16
    const float* __restrict__ brfbb,   // [128]
    float* __restrict__ out,           // [4096,1024]
    float* __restrict__ rf2bb)         // [4096,128] fp32
{
    __shared__ short Ah[2][128 * LDW];
    __shared__ short Bh[2][64 * LDW];
    __shared__ short Wh[2][16 * LDW];
    int tid = threadIdx.x;
    int wave = tid >> 6, lane = tid & 63;
    int r = lane & 15, quad = lane >> 4, q8 = quad * 8;
    int wm = (wave & 1) * 64, wn = (wave >> 1) * 32;
    int mt = blockIdx.x >> 4, nt = blockIdx.x & 15;
    int m0 = mt * 128, n0 = nt * 64;
    bool doP = (nt < 8);
    bool doW = doP && (wave < 2);
    bool wload = doP && (tid < 128);

    // staging register file
    short8 ra[4], rb[2], rw;
    // staging addresses (thread-constant)
    int aRow = tid >> 1, aOff = (tid & 1) * 32;       // A: 128 rows x 64 shorts
    int bRow = tid >> 2, bOff = (tid & 3) * 16;       // B: 64 rows
    int wRow = tid >> 3, wOff = (tid & 7) * 8;        // W: 16 rows (tid<128)

    const short* aBase = rfh    + (size_t)(m0 + aRow) * RDIM + aOff;
    const short* bBase = wrfrfh + (size_t)(n0 + bRow) * RDIM + bOff;
    const short* wBase = wrfbbh + (size_t)(nt * 16 + wRow) * RDIM + wOff;

    floatx4 acc1[4][2], acc2[4][2], acc3[4];
    #pragma unroll
    for (int mi = 0; mi < 4; ++mi) {
        acc1[mi][0] = floatx4{0.f,0.f,0.f,0.f}; acc1[mi][1] = acc1[mi][0];
        acc2[mi][0] = acc1[mi][0]; acc2[mi][1] = acc1[mi][0];
        acc3[mi] = acc1[mi][0];
    }

    auto loadG1 = [&](int kt) {
        int kb = kt * 64;
        const short8* pa = (const short8*)(aBase + kb);
        ra[0] = pa[0]; ra[1] = pa[1]; ra[2] = pa[2]; ra[3] = pa[3];
        const short8* pb = (const short8*)(bBase + kb);
        rb[0] = pb[0]; rb[1] = pb[1];
        if (wload) rw = *(const short8*)(wBase + kb);
    };
    auto storeT = [&](int buf, bool withW) {
        short* Ad = &Ah[buf][aRow * LDW + aOff];
        *(short8*)(Ad)      = ra[0]; *(short8*)(Ad + 8)  = ra[1];
        *(short8*)(Ad + 16) = ra[2]; *(short8*)(Ad + 24) = ra[3];
        short* Bd = &Bh[buf][bRow * LDW + bOff];
        *(short8*)(Bd) = rb[0]; *(short8*)(Bd + 8) = rb[1];
        if (withW && wload) *(short8*)&Wh[buf][wRow * LDW + wOff] = rw;
    };

#define COMPUTE_G1(BUF)                                                        \
    { _Pragma("unroll")                                                        \
      for (int c = 0; c < 2; ++c) {                                            \
        short8 af[4], bf[2];                                                   \
        _Pragma("unroll")                                                      \
        for (int mi = 0; mi < 4; ++mi)                                         \
            af[mi] = *(const short8*)&Ah[BUF][(wm + mi*16 + r) * LDW + c*32 + q8]; \
        bf[0] = *(const short8*)&Bh[BUF][(wn + r) * LDW + c*32 + q8];          \
        bf[1] = *(const short8*)&Bh[BUF][(wn + 16 + r) * LDW + c*32 + q8];     \
        _Pragma("unroll")                                                      \
        for (int mi = 0; mi < 4; ++mi) {                                       \
            acc1[mi][0] = MFMA(af[mi], bf[0], acc1[mi][0]);                    \
            acc1[mi][1] = MFMA(af[mi], bf[1], acc1[mi][1]);                    \
        }                                                                      \
        if (doW) {                                                             \
            short8 wf = *(const short8*)&Wh[BUF][r * LDW + c*32 + q8];         \
            _Pragma("unroll")                                                  \
            for (int mi = 0; mi < 4; ++mi) acc3[mi] = MFMA(af[mi], wf, acc3[mi]); \
        }                                                                      \
      } }

#define COMPUTE_G2(BUF)                                                        \
    { _Pragma("unroll")                                                        \
      for (int c = 0; c < 2; ++c) {                                            \
        short8 af[4], bf[2];                                                   \
        _Pragma("unroll")                                                      \
        for (int mi = 0; mi < 4; ++mi)                                         \
            af[mi] = *(const short8*)&Ah[BUF][(wm + mi*16 + r) * LDW + c*32 + q8]; \
        bf[0] = *(const short8*)&Bh[BUF][(wn + r) * LDW + c*32 + q8];          \
        bf[1] = *(const short8*)&Bh[BUF][(wn + 16 + r) * LDW + c*32 + q8];     \
        _Pragma("unroll")                                                      \
        for (int mi = 0; mi < 4; ++mi) {                                       \
            acc2[mi][0] = MFMA(af[mi], bf[0], acc2[mi][0]);                    \
            acc2[mi][1] = MFMA(af[mi], bf[1], acc2[mi][1]);                    \
        }                                                                      \
      } }

    // ---- GEMM1 (+G3 piggyback): K=1024, 16 tiles of BK=64 ----
    loadG1(0); storeT(0, true); loadG1(1);
    __syncthreads();
    for (int it2 = 0; it2 < 8; ++it2) {
        COMPUTE_G1(0)
        { int kt = it2 * 2 + 2; if (kt > 15) kt = 15;
          storeT(1, true); loadG1(kt); }
        __syncthreads();
        COMPUTE_G1(1)
        { int kt = it2 * 2 + 3; if (kt > 15) kt = 15;
          storeT(0, true); loadG1(kt); }
        __syncthreads();
    }

    // ---- GEMM2: mean @ Wbbrf^T, K=128 = 2 tiles ----
    {
        const short* a2 = meanh  + (size_t)(m0 + aRow) * BDIM + aOff;
        const short* b2 = wbbrfh + (size_t)(n0 + bRow) * BDIM + bOff;
        const short8* pa = (const short8*)a2;
        ra[0] = pa[0]; ra[1] = pa[1]; ra[2] = pa[2]; ra[3] = pa[3];
        const short8* pb = (const short8*)b2;
        rb[0] = pb[0]; rb[1] = pb[1];
        storeT(0, false);
        pa = (const short8*)(a2 + 64);
        ra[0] = pa[0]; ra[1] = pa[1]; ra[2] = pa[2]; ra[3] = pa[3];
        pb = (const short8*)(b2 + 64);
        rb[0] = pb[0]; rb[1] = pb[1];
        __syncthreads();
        COMPUTE_G2(0)
        storeT(1, false);
        __syncthreads();
        COMPUTE_G2(1)
    }

    // ---- epilogue ----
    #pragma unroll
    for (int nj = 0; nj < 2; ++nj) {
        int col = n0 + wn + nj * 16 + r;
        float b1 = brfrf[col];
        float b2 = bbbrf[col];
        #pragma unroll
        for (int mi = 0; mi < 4; ++mi) {
            #pragma unroll
            for (int g = 0; g < 4; ++g) {
                int row = m0 + wm + mi * 16 + quad * 4 + g;
                out[(size_t)row * RDIM + col] =
                    mishf(acc1[mi][nj][g] + b1) + mishf(acc2[mi][nj][g] + b2);
            }
        }
    }
    if (doW) {
        int col = nt * 16 + r;
        float bs = brfbb[col];
        #pragma unroll
        for (int mi = 0; mi < 4; ++mi) {
            #pragma unroll
            for (int g = 0; g < 4; ++g) {
                int row = m0 + wm + mi * 16 + quad * 4 + g;
                rf2bb[(size_t)row * BDIM + col] = mishf(acc3[mi][g] + bs);
            }
        }
    }
#undef COMPUTE_G1
#undef COMPUTE_G2
}

// ---------------- new_BB = mish(BB @ W_bbbb^T + b) + RF_to_BB[b] ----------------
// 1024 blocks x 256 thr; wave-per-16-rows; W in LDS (staged once); no loop barriers.
__global__ void __launch_bounds__(256) k_newbb(
    const float* __restrict__ bb,      // [65536,128] fp32
    const short* __restrict__ wbbbbh,  // [128,128] bf16
    const float* __restrict__ bias,    // [128]
    const float* __restrict__ rf2bb,   // [4096,128] fp32
    float* __restrict__ out)           // [65536,128]
{
    __shared__ short Wt[128 * WST];
    int tid = threadIdx.x, wave = tid >> 6, lane = tid & 63;
    int r = lane & 15, quad = lane >> 4, q8 = quad * 8;
    {
        int row = tid >> 1, half = (tid & 1) * 64;
        const short* src = wbbbbh + (size_t)row * BDIM + half;
        short* dst = &Wt[row * WST + half];
        #pragma unroll
        for (int j = 0; j < 8; ++j)
            *(short8*)(dst + j * 8) = *(const short8*)(src + j * 8);
    }
    size_t m0 = (size_t)blockIdx.x * 64 + wave * 16;
    const float* ap = bb + (m0 + r) * BDIM + q8;
    float4 f[8];
    #pragma unroll
    for (int c = 0; c < 4; ++c) {
        f[2*c]     = ((const float4*)(ap + c * 32))[0];
        f[2*c + 1] = ((const float4*)(ap + c * 32))[1];
    }
    __syncthreads();
    short8 af[4];
    #pragma unroll
    for (int c = 0; c < 4; ++c) af[c] = cvt8v(f[2*c], f[2*c + 1]);
    floatx4 acc[8];
    #pragma unroll
    for (int j = 0; j < 8; ++j) acc[j] = floatx4{0.f,0.f,0.f,0.f};
    #pragma unroll
    for (int c = 0; c < 4; ++c) {
        #pragma unroll
        for (int nj = 0; nj < 8; ++nj) {
            short8 b = *(const short8*)&Wt[(nj * 16 + r) * WST + c * 32 + q8];
            acc[nj] = MFMA(af[c], b, acc[nj]);
        }
    }
    size_t bidx = m0 >> 4;   // uniform per wave
    #pragma unroll
    for (int nj = 0; nj < 8; ++nj) {
        int col = nj * 16 + r;
        float bs = bias[col];
        float rv = rf2bb[bidx * BDIM + col];
        #pragma unroll
        for (int g = 0; g < 4; ++g) {
            size_t row = m0 + quad * 4 + g;
            out[row * BDIM + col] = mishf(acc[nj][g] + bs) + rv;
        }
    }
}

extern "C" void kernel_launch(void* const* d_in, const int* in_sizes, int n_in,
                              void* d_out, int out_size, void* d_ws, size_t ws_size,
                              hipStream_t stream) {
    const float* BB    = (const float*)d_in[0];
    const float* RF    = (const float*)d_in[1];
    const float* Wrfbb = (const float*)d_in[2];
    const float* brfbb = (const float*)d_in[3];
    const float* Wrfrf = (const float*)d_in[4];
    const float* brfrf = (const float*)d_in[5];
    const float* Wbbrf = (const float*)d_in[6];
    const float* bbbrf = (const float*)d_in[7];
    const float* Wbbbb = (const float*)d_in[8];
    const float* bbbbb = (const float*)d_in[9];

    float* outBB = (float*)d_out;
    float* outRF = outBB + (size_t)NB * NG * BDIM;

    char* ws = (char*)d_ws;
    short* meanh  = (short*)(ws + OFF_MEANH);
    short* rfh    = (short*)(ws + OFF_RFH);
    short* wrfrfh = (short*)(ws + OFF_WRFRFH);
    short* wbbrfh = (short*)(ws + OFF_WBBRFH);
    short* wrfbbh = (short*)(ws + OFF_WRFBBH);
    short* wbbbbh = (short*)(ws + OFF_WBBBBH);
    float* rf2bb  = (float*)(ws + OFF_RF2BB);

    k_prep <<<1600, 256, 0, stream>>>(BB, RF, Wrfrf, Wbbrf, Wrfbb, Wbbbb,
                                      meanh, rfh, wrfrfh, wbbrfh, wrfbbh, wbbbbh);
    k_newrf<<<512,  256, 0, stream>>>(rfh, meanh, wrfrfh, brfrf, wbbrfh, bbbrf,
                                      wrfbbh, brfbb, outRF, rf2bb);
    k_newbb<<<1024, 256, 0, stream>>>(BB, wbbbbh, bbbbb, rf2bb, outBB);
}